// Round 1
// baseline (682.351 us; speedup 1.0000x reference)
//
#include <hip/hip_runtime.h>

// SpectralDivergence: fft2(512x512) power spectrum -> radial profile (50 bins)
// -> per-batch KL divergence between softmaxed profiles of x and reference.
// 96 images total (48 x + 48 ref), B=16, C=3, H=W=512. Output: 16 floats.

#define HH 512
#define WW 512
#define NIMG 96     // 2 * 16 * 3
#define NB 50

__device__ __forceinline__ float2 cmul_w(float2 a, float cw, float sw) {
  // a * (cw + i*sw)
  return make_float2(a.x * cw - a.y * sw, a.x * sw + a.y * cw);
}

// ---------------------------------------------------------------------------
// Kernel 1: 512-point row FFTs (real input), Stockham radix-2 in LDS.
// One block = 4 consecutive rows of one image (256 threads, 1 butterfly/row).
// Output written TRANSPOSED: outT[img][col][row] so kernel 2 reads contiguous.
// ---------------------------------------------------------------------------
__global__ __launch_bounds__(256) void fft_rows_T(
    const float* __restrict__ xin, const float* __restrict__ rin,
    float2* __restrict__ outT, int img0)
{
  const int t     = threadIdx.x;
  const int gid   = blockIdx.x;
  const int local = gid >> 7;    // image within chunk (128 row-groups/image)
  const int rg    = gid & 127;   // row group (4 rows each)
  const int img   = img0 + local;

  const float* src = (img < 48)
      ? (xin + (size_t)img * (size_t)(HH * WW))
      : (rin + (size_t)(img - 48) * (size_t)(HH * WW));
  src += (size_t)rg * (4 * WW);

  __shared__ float2 bufA[4][512];
  __shared__ float2 bufB[4][512];

  // coalesced load: thread t loads elements 2t, 2t+1 of each of 4 rows
  #pragma unroll
  for (int q = 0; q < 4; ++q) {
    float2 v = reinterpret_cast<const float2*>(src + q * WW)[t];
    bufA[q][2 * t]     = make_float2(v.x, 0.f);
    bufA[q][2 * t + 1] = make_float2(v.y, 0.f);
  }
  __syncthreads();

  float2 (*s)[512] = bufA;
  float2 (*d)[512] = bufB;
  int l = 256, m = 1;
  #pragma unroll
  for (int st = 0; st < 9; ++st) {
    const int j = t / m;              // m is a power of two (unrolled -> shift)
    float sw, cw;
    __sincosf(-3.14159265358979f * (float)j / (float)l, &sw, &cw);
    const int o0 = t + j * m;
    #pragma unroll
    for (int q = 0; q < 4; ++q) {
      float2 c0 = s[q][t];
      float2 c1 = s[q][t + 256];
      d[q][o0]     = make_float2(c0.x + c1.x, c0.y + c1.y);
      float2 df    = make_float2(c0.x - c1.x, c0.y - c1.y);
      d[q][o0 + m] = cmul_w(df, cw, sw);
    }
    __syncthreads();
    float2 (*tmp)[512] = s; s = d; d = tmp;
    l >>= 1; m <<= 1;
  }
  // result in s. Transposed write: for each col c, 4 consecutive rows = 32 B.
  const size_t base = (size_t)local * 512 * 512 + (size_t)rg * 4;
  #pragma unroll
  for (int cc = 0; cc < 2; ++cc) {
    const int c = t + cc * 256;
    float2 v0 = s[0][c], v1 = s[1][c], v2 = s[2][c], v3 = s[3][c];
    float4* dst = reinterpret_cast<float4*>(outT + (base + (size_t)c * 512));
    dst[0] = make_float4(v0.x, v0.y, v1.x, v1.y);
    dst[1] = make_float4(v2.x, v2.y, v3.x, v3.y);
  }
}

// ---------------------------------------------------------------------------
// Kernel 2: 512-point column FFTs on transposed data (contiguous loads),
// fused |F|^2 + radial binning. One block = 8 columns (sequential) of one
// image; per-block LDS bin accumulator, one global atomic flush of 50 floats.
// ---------------------------------------------------------------------------
__global__ __launch_bounds__(256) void fft_cols_bin(
    const float2* __restrict__ inT, float* __restrict__ profSum, int img0)
{
  const int t     = threadIdx.x;
  const int gid   = blockIdx.x;
  const int local = gid >> 6;    // image within chunk (64 col-groups/image)
  const int cg    = gid & 63;    // column group (8 cols each)
  const int imgG  = img0 + local;

  __shared__ float2 bufA[512];
  __shared__ float2 bufB[512];
  __shared__ float  bins[NB];
  if (t < NB) bins[t] = 0.f;

  for (int u = 0; u < 8; ++u) {
    const int c = cg * 8 + u;
    const float2* src = inT + ((size_t)(local * 512 + c) * 512);
    float4 v = reinterpret_cast<const float4*>(src)[t];
    bufA[2 * t]     = make_float2(v.x, v.y);
    bufA[2 * t + 1] = make_float2(v.z, v.w);
    __syncthreads();

    float2* ss = bufA;
    float2* dd = bufB;
    int l = 256, m = 1;
    #pragma unroll
    for (int st = 0; st < 9; ++st) {
      const int j = t / m;
      float sw, cw;
      __sincosf(-3.14159265358979f * (float)j / (float)l, &sw, &cw);
      const int o0 = t + j * m;
      float2 c0 = ss[t];
      float2 c1 = ss[t + 256];
      dd[o0]     = make_float2(c0.x + c1.x, c0.y + c1.y);
      float2 df  = make_float2(c0.x - c1.x, c0.y - c1.y);
      dd[o0 + m] = cmul_w(df, cw, sw);
      __syncthreads();
      float2* tmp = ss; ss = dd; dd = tmp;
      l >>= 1; m <<= 1;
    }
    // result in ss (= bufB). Power + radial bin. Frequencies: this line runs
    // over row-freq fy = e; column freq fx = c. Signed (fftshift-relative).
    const int sx  = (c < 256) ? c : c - 512;
    const int sx2 = sx * sx;
    #pragma unroll
    for (int e2 = 0; e2 < 2; ++e2) {
      const int e  = t + e2 * 256;
      float2 F = ss[e];
      float p = F.x * F.x + F.y * F.y;
      const int sy = (e < 256) ? e : e - 512;
      float r = sqrtf((float)(sy * sy + sx2));
      int bb = (int)(r * 0.1953125f);   // 50/256 exact in binary
      if (bb < NB) atomicAdd(&bins[bb], p);
    }
    __syncthreads();   // bufA rewrite next iter; also orders binning reads
  }
  if (t < NB) atomicAdd(&profSum[(size_t)imgG * NB + t], bins[t]);
}

// ---------------------------------------------------------------------------
// Kernel 3: counts -> profile means -> log_softmax -> KL. One block per batch.
// ---------------------------------------------------------------------------
__global__ __launch_bounds__(256) void finalize_kl(
    const float* __restrict__ profSum, float* __restrict__ out)
{
  const int b = blockIdx.x;
  const int t = threadIdx.x;
  __shared__ float cnt[NB];
  __shared__ float red[256];
  if (t < NB) cnt[t] = 0.f;
  __syncthreads();
  for (int idx = t; idx < HH * WW; idx += 256) {
    const int y  = idx >> 9;
    const int xx = idx & 511;
    const int sy = (y < 256) ? y : y - 512;
    const int sx = (xx < 256) ? xx : xx - 512;
    float r = sqrtf((float)(sy * sy + sx * sx));
    int bb = (int)(r * 0.1953125f);
    if (bb < NB) atomicAdd(&cnt[bb], 1.f);
  }
  __syncthreads();

  float lxv = -3.0e38f, lrv = -3.0e38f;
  if (t < 150) {
    const int cc  = t / NB;
    const int bin = t - cc * NB;
    const float c = cnt[bin];
    lxv = profSum[(size_t)(b * 3 + cc) * NB + bin] / c;
    lrv = profSum[(size_t)(48 + b * 3 + cc) * NB + bin] / c;
  }

  auto rmax = [&](float v) {
    red[t] = v; __syncthreads();
    for (int s2 = 128; s2 >= 1; s2 >>= 1) {
      if (t < s2) red[t] = fmaxf(red[t], red[t + s2]);
      __syncthreads();
    }
    float rr = red[0]; __syncthreads();
    return rr;
  };
  auto rsum = [&](float v) {
    red[t] = v; __syncthreads();
    for (int s2 = 128; s2 >= 1; s2 >>= 1) {
      if (t < s2) red[t] = red[t] + red[t + s2];
      __syncthreads();
    }
    float rr = red[0]; __syncthreads();
    return rr;
  };

  const float mx  = rmax(lxv);
  const float mr  = rmax(lrv);
  const float sx  = rsum((t < 150) ? expf(lxv - mx) : 0.f);
  const float sr  = rsum((t < 150) ? expf(lrv - mr) : 0.f);
  const float lsx = logf(sx);
  const float lsr = logf(sr);
  float term = 0.f;
  if (t < 150) {
    const float logp = lxv - mx - lsx;
    const float logq = lrv - mr - lsr;
    const float q    = expf(logq);
    term = q * (logq - logp);
  }
  const float div = rsum(term);
  if (t == 0) out[b] = div;
}

// ---------------------------------------------------------------------------
extern "C" void kernel_launch(void* const* d_in, const int* in_sizes, int n_in,
                              void* d_out, int out_size, void* d_ws, size_t ws_size,
                              hipStream_t stream)
{
  const float* x = (const float*)d_in[0];
  const float* r = (const float*)d_in[1];
  float* out     = (float*)d_out;

  // ws layout: [0, 19200) profile sums (96 imgs x 50 bins), then (aligned)
  // chunked transposed-spectrum intermediate, 2 MB per image.
  float* profSum = (float*)d_ws;
  const size_t IM_OFS = 19456;
  float2* interT = (float2*)((char*)d_ws + IM_OFS);

  const size_t perImg = (size_t)HH * WW * sizeof(float2);  // 2 MiB
  size_t avail = (ws_size > IM_OFS) ? (ws_size - IM_OFS) : 0;
  int ic = (int)(avail / perImg);
  if (ic > NIMG) ic = NIMG;
  if (ic < 1) ic = 1;

  hipMemsetAsync(d_ws, 0, (size_t)NIMG * NB * sizeof(float), stream);

  for (int img0 = 0; img0 < NIMG; img0 += ic) {
    const int n = (NIMG - img0 < ic) ? (NIMG - img0) : ic;
    hipLaunchKernelGGL(fft_rows_T, dim3(n * 128), dim3(256), 0, stream,
                       x, r, interT, img0);
    hipLaunchKernelGGL(fft_cols_bin, dim3(n * 64), dim3(256), 0, stream,
                       interT, profSum, img0);
  }
  hipLaunchKernelGGL(finalize_kl, dim3(16), dim3(256), 0, stream, profSum, out);
}

// Round 2
// 205.408 us; speedup vs baseline: 3.3219x; 3.3219x over previous
//
#include <hip/hip_runtime.h>

// SpectralDivergence: fft2(512x512) power spectrum -> radial profile (50 bins)
// -> per-batch KL divergence between softmaxed profiles of x and reference.
// 96 images total (48 x + 48 ref), B=16, C=3, H=W=512. Output: 16 floats.
//
// R1: (a) bin-count computation moved out of finalize_kl (was 343us of 682us:
//     262144-pixel loop on 16 blocks with contended LDS atomics) into a
//     parallel one-shot kernel; (b) Hermitian symmetry: real input => power
//     spectrum is negation-symmetric, so column FFTs run only for fx=0..256
//     with x2 weight on fx=1..255. Halves kernel-2 work and intermediate.

#define HH 512
#define WW 512
#define NIMG 96     // 2 * 16 * 3
#define NB 50
#define NCOL 257    // Hermitian: columns 0..256
#define CG_PER_IMG 33  // ceil(257/8)

__device__ __forceinline__ float2 cmul_w(float2 a, float cw, float sw) {
  return make_float2(a.x * cw - a.y * sw, a.x * sw + a.y * cw);
}

// ---------------------------------------------------------------------------
// Kernel 1: 512-point row FFTs (real input), Stockham radix-2 in LDS.
// One block = 4 consecutive rows of one image (256 threads, 1 butterfly/row).
// Output TRANSPOSED, columns 0..256 only: outT[img][col][row].
// ---------------------------------------------------------------------------
__global__ __launch_bounds__(256) void fft_rows_T(
    const float* __restrict__ xin, const float* __restrict__ rin,
    float2* __restrict__ outT, int img0)
{
  const int t     = threadIdx.x;
  const int gid   = blockIdx.x;
  const int local = gid >> 7;    // image within chunk (128 row-groups/image)
  const int rg    = gid & 127;   // row group (4 rows each)
  const int img   = img0 + local;

  const float* src = (img < 48)
      ? (xin + (size_t)img * (size_t)(HH * WW))
      : (rin + (size_t)(img - 48) * (size_t)(HH * WW));
  src += (size_t)rg * (4 * WW);

  __shared__ float2 bufA[4][512];
  __shared__ float2 bufB[4][512];

  #pragma unroll
  for (int q = 0; q < 4; ++q) {
    float2 v = reinterpret_cast<const float2*>(src + q * WW)[t];
    bufA[q][2 * t]     = make_float2(v.x, 0.f);
    bufA[q][2 * t + 1] = make_float2(v.y, 0.f);
  }
  __syncthreads();

  float2 (*s)[512] = bufA;
  float2 (*d)[512] = bufB;
  int l = 256, m = 1;
  #pragma unroll
  for (int st = 0; st < 9; ++st) {
    const int j = t / m;
    float sw, cw;
    __sincosf(-3.14159265358979f * (float)j / (float)l, &sw, &cw);
    const int o0 = t + j * m;
    #pragma unroll
    for (int q = 0; q < 4; ++q) {
      float2 c0 = s[q][t];
      float2 c1 = s[q][t + 256];
      d[q][o0]     = make_float2(c0.x + c1.x, c0.y + c1.y);
      float2 df    = make_float2(c0.x - c1.x, c0.y - c1.y);
      d[q][o0 + m] = cmul_w(df, cw, sw);
    }
    __syncthreads();
    float2 (*tmp)[512] = s; s = d; d = tmp;
    l >>= 1; m <<= 1;
  }
  // Transposed write, cols 0..256 only: 4 consecutive rows = 32 B per col.
  const size_t base = (size_t)local * ((size_t)NCOL * 512) + (size_t)rg * 4;
  #pragma unroll
  for (int cc = 0; cc < 2; ++cc) {
    const int c = t + cc * 256;
    if (c <= 256) {
      float2 v0 = s[0][c], v1 = s[1][c], v2 = s[2][c], v3 = s[3][c];
      float4* dst = reinterpret_cast<float4*>(outT + (base + (size_t)c * 512));
      dst[0] = make_float4(v0.x, v0.y, v1.x, v1.y);
      dst[1] = make_float4(v2.x, v2.y, v3.x, v3.y);
    }
  }
}

// ---------------------------------------------------------------------------
// Kernel 2: 512-point column FFTs on transposed data (contiguous loads),
// fused |F|^2 + radial binning with Hermitian weight. One block = up to 8
// columns of one image; per-block LDS bins, one global atomic flush.
// ---------------------------------------------------------------------------
__global__ __launch_bounds__(256) void fft_cols_bin(
    const float2* __restrict__ inT, float* __restrict__ profSum, int img0)
{
  const int t     = threadIdx.x;
  const int gid   = blockIdx.x;
  const int local = gid / CG_PER_IMG;
  const int cg    = gid - local * CG_PER_IMG;
  const int imgG  = img0 + local;

  __shared__ float2 bufA[512];
  __shared__ float2 bufB[512];
  __shared__ float  bins[NB];
  if (t < NB) bins[t] = 0.f;

  for (int u = 0; u < 8; ++u) {
    const int c = cg * 8 + u;
    if (c > 256) break;                    // block-uniform
    const float2* src = inT + ((size_t)(local * NCOL + c) * 512);
    float4 v = reinterpret_cast<const float4*>(src)[t];
    bufA[2 * t]     = make_float2(v.x, v.y);
    bufA[2 * t + 1] = make_float2(v.z, v.w);
    __syncthreads();

    float2* ss = bufA;
    float2* dd = bufB;
    int l = 256, m = 1;
    #pragma unroll
    for (int st = 0; st < 9; ++st) {
      const int j = t / m;
      float sw, cw;
      __sincosf(-3.14159265358979f * (float)j / (float)l, &sw, &cw);
      const int o0 = t + j * m;
      float2 c0 = ss[t];
      float2 c1 = ss[t + 256];
      dd[o0]     = make_float2(c0.x + c1.x, c0.y + c1.y);
      float2 df  = make_float2(c0.x - c1.x, c0.y - c1.y);
      dd[o0 + m] = cmul_w(df, cw, sw);
      __syncthreads();
      float2* tmp = ss; ss = dd; dd = tmp;
      l >>= 1; m <<= 1;
    }
    // Hermitian weight: fx=0 and fx=256 columns are self-paired (w=1);
    // fx=1..255 represent both fx and 512-fx (w=2).
    const float wf = (c == 0 || c == 256) ? 1.f : 2.f;
    const int sx  = (c < 256) ? c : c - 512;
    const int sx2 = sx * sx;
    #pragma unroll
    for (int e2 = 0; e2 < 2; ++e2) {
      const int e  = t + e2 * 256;
      float2 F = ss[e];
      float p = wf * (F.x * F.x + F.y * F.y);
      const int sy = (e < 256) ? e : e - 512;
      float r = sqrtf((float)(sy * sy + sx2));
      int bb = (int)(r * 0.1953125f);   // 50/256 exact in binary
      if (bb < NB) atomicAdd(&bins[bb], p);
    }
    __syncthreads();
  }
  if (t < NB) atomicAdd(&profSum[(size_t)imgG * NB + t], bins[t]);
}

// ---------------------------------------------------------------------------
// Kernel C: radial bin counts (geometry only). 128 blocks x 2048 pixels.
// ---------------------------------------------------------------------------
__global__ __launch_bounds__(256) void compute_counts(float* __restrict__ cnt)
{
  const int t = threadIdx.x;
  __shared__ float lb[NB];
  if (t < NB) lb[t] = 0.f;
  __syncthreads();
  const int base = blockIdx.x * 2048;
  #pragma unroll
  for (int k = 0; k < 8; ++k) {
    const int idx = base + k * 256 + t;
    const int y  = idx >> 9;
    const int xx = idx & 511;
    const int sy = (y < 256) ? y : y - 512;
    const int sx = (xx < 256) ? xx : xx - 512;
    float r = sqrtf((float)(sy * sy + sx * sx));
    int bb = (int)(r * 0.1953125f);
    if (bb < NB) atomicAdd(&lb[bb], 1.f);
  }
  __syncthreads();
  if (t < NB) atomicAdd(&cnt[t], lb[t]);
}

// ---------------------------------------------------------------------------
// Kernel 3: profile means -> log_softmax -> KL. One block per batch.
// ---------------------------------------------------------------------------
__global__ __launch_bounds__(256) void finalize_kl(
    const float* __restrict__ profSum, const float* __restrict__ cntg,
    float* __restrict__ out)
{
  const int b = blockIdx.x;
  const int t = threadIdx.x;
  __shared__ float red[256];

  float lxv = -3.0e38f, lrv = -3.0e38f;
  if (t < 150) {
    const int cc  = t / NB;
    const int bin = t - cc * NB;
    const float c = cntg[bin];
    lxv = profSum[(size_t)(b * 3 + cc) * NB + bin] / c;
    lrv = profSum[(size_t)(48 + b * 3 + cc) * NB + bin] / c;
  }

  auto rmax = [&](float v) {
    red[t] = v; __syncthreads();
    for (int s2 = 128; s2 >= 1; s2 >>= 1) {
      if (t < s2) red[t] = fmaxf(red[t], red[t + s2]);
      __syncthreads();
    }
    float rr = red[0]; __syncthreads();
    return rr;
  };
  auto rsum = [&](float v) {
    red[t] = v; __syncthreads();
    for (int s2 = 128; s2 >= 1; s2 >>= 1) {
      if (t < s2) red[t] = red[t] + red[t + s2];
      __syncthreads();
    }
    float rr = red[0]; __syncthreads();
    return rr;
  };

  const float mx  = rmax(lxv);
  const float mr  = rmax(lrv);
  const float sx  = rsum((t < 150) ? expf(lxv - mx) : 0.f);
  const float sr  = rsum((t < 150) ? expf(lrv - mr) : 0.f);
  const float lsx = logf(sx);
  const float lsr = logf(sr);
  float term = 0.f;
  if (t < 150) {
    const float logp = lxv - mx - lsx;
    const float logq = lrv - mr - lsr;
    const float q    = expf(logq);
    term = q * (logq - logp);
  }
  const float div = rsum(term);
  if (t == 0) out[b] = div;
}

// ---------------------------------------------------------------------------
extern "C" void kernel_launch(void* const* d_in, const int* in_sizes, int n_in,
                              void* d_out, int out_size, void* d_ws, size_t ws_size,
                              hipStream_t stream)
{
  const float* x = (const float*)d_in[0];
  const float* r = (const float*)d_in[1];
  float* out     = (float*)d_out;

  // ws layout: [0,19200) profile sums (96x50); [19200,19400) bin counts;
  // [19456, ...) chunked transposed-spectrum intermediate (257 cols/img).
  float* profSum = (float*)d_ws;
  float* cnt     = (float*)((char*)d_ws + 19200);
  const size_t IM_OFS = 19456;
  float2* interT = (float2*)((char*)d_ws + IM_OFS);

  const size_t perImg = (size_t)NCOL * 512 * sizeof(float2);  // ~1.03 MiB
  size_t avail = (ws_size > IM_OFS) ? (ws_size - IM_OFS) : 0;
  int ic = (int)(avail / perImg);
  if (ic > NIMG) ic = NIMG;
  if (ic < 1) ic = 1;

  hipMemsetAsync(d_ws, 0, IM_OFS, stream);
  hipLaunchKernelGGL(compute_counts, dim3(128), dim3(256), 0, stream, cnt);

  for (int img0 = 0; img0 < NIMG; img0 += ic) {
    const int n = (NIMG - img0 < ic) ? (NIMG - img0) : ic;
    hipLaunchKernelGGL(fft_rows_T, dim3(n * 128), dim3(256), 0, stream,
                       x, r, interT, img0);
    hipLaunchKernelGGL(fft_cols_bin, dim3(n * CG_PER_IMG), dim3(256), 0, stream,
                       interT, profSum, img0);
  }
  hipLaunchKernelGGL(finalize_kl, dim3(16), dim3(256), 0, stream,
                     profSum, cnt, out);
}

// Round 3
// 153.365 us; speedup vs baseline: 4.4492x; 1.3393x over previous
//
#include <hip/hip_runtime.h>

// SpectralDivergence: fft2(512x512) power spectrum -> radial profile (50 bins)
// -> per-batch KL divergence between softmaxed profiles of x and reference.
// 96 images (48 x + 48 ref), B=16, C=3, H=W=512. Output: 16 floats.
//
// R2: wave-local radix-8 FFT (512 = 8*8*8). One wave = one 512-pt FFT:
// 8 complex regs/lane, 3 register radix-8 stages, 2 LDS exchanges with
// XOR-swizzled conflict-free layouts, NO __syncthreads (wave-synchronous,
// per-wave in-order DS pipeline). Twiddles hoisted (2 sincos per wave).
// Row pass packs 2 real rows into 1 complex FFT (conjugate-symmetry split).

#define NIMG 96
#define NB 50
#define NCOL 257

__device__ __forceinline__ float2 cadd(float2 a, float2 b){ return make_float2(a.x+b.x, a.y+b.y); }
__device__ __forceinline__ float2 csub(float2 a, float2 b){ return make_float2(a.x-b.x, a.y-b.y); }
__device__ __forceinline__ float2 cmul(float2 a, float2 b){
  return make_float2(fmaf(a.x, b.x, -(a.y*b.y)), fmaf(a.x, b.y, a.y*b.x));
}
__device__ __forceinline__ float2 mul_mi(float2 a){ return make_float2(a.y, -a.x); }  // * -i

// 8-point DFT, natural order: g[r] <- sum_a g[a] * W8^{a r}
__device__ __forceinline__ void fft8(float2 g[8]) {
  const float C = 0.70710678118654752f;
  float2 e0=g[0], e1=g[2], e2=g[4], e3=g[6];
  float2 o0=g[1], o1=g[3], o2=g[5], o3=g[7];
  float2 t0=cadd(e0,e2), t1=csub(e0,e2), t2=cadd(e1,e3), t3m=mul_mi(csub(e1,e3));
  float2 E0=cadd(t0,t2), E1=cadd(t1,t3m), E2=csub(t0,t2), E3=csub(t1,t3m);
  float2 s0=cadd(o0,o2), s1=csub(o0,o2), s2=cadd(o1,o3), s3m=mul_mi(csub(o1,o3));
  float2 O0=cadd(s0,s2), O1=cadd(s1,s3m), O2=csub(s0,s2), O3=csub(s1,s3m);
  O1 = make_float2(C*(O1.x+O1.y), C*(O1.y-O1.x));      // * W8^1
  O2 = mul_mi(O2);                                      // * W8^2
  O3 = make_float2(C*(O3.y-O3.x), -C*(O3.x+O3.y));      // * W8^3
  g[0]=cadd(E0,O0); g[4]=csub(E0,O0);
  g[1]=cadd(E1,O1); g[5]=csub(E1,O1);
  g[2]=cadd(E2,O2); g[6]=csub(E2,O2);
  g[3]=cadd(E3,O3); g[7]=csub(E3,O3);
}

// Wave-local 512-pt FFT. Input: x[a] = data[64a + lane]. Output:
// x[q] = X[(lane>>3) + 8*(lane&7) + 64*q]. re/im: per-wave 512-float arrays.
// Exchange layouts (both conflict-free, <=2 lanes/bank):
//   ex1: idx = 64r + 8*(a'^r) + b''      (lane = 8a' + b'' writes; 8r+b'' reads)
//   ex2: idx = 64r + 8*(r'^r) + (b''^r') (lane = 8r+b'' writes; 8r+r' reads)
__device__ __forceinline__ void wave_fft512(
    float2 x[8], float* __restrict__ re, float* __restrict__ im,
    const float2 tw1[7], const float2 tw2[7], int lane)
{
  const int hi = lane >> 3, lo = lane & 7;
  fft8(x);
  #pragma unroll
  for (int r = 1; r < 8; ++r) x[r] = cmul(x[r], tw1[r-1]);
  #pragma unroll
  for (int r = 0; r < 8; ++r) {            // writer: a'=hi, b''=lo
    int idx = 64*r + 8*(hi ^ r) + lo;
    re[idx] = x[r].x; im[idx] = x[r].y;
  }
  __builtin_amdgcn_wave_barrier();
  #pragma unroll
  for (int ap = 0; ap < 8; ++ap) {         // reader: r=hi, b''=lo
    int idx = 64*hi + 8*(ap ^ hi) + lo;
    x[ap] = make_float2(re[idx], im[idx]);
  }
  __builtin_amdgcn_wave_barrier();
  fft8(x);
  #pragma unroll
  for (int rp = 1; rp < 8; ++rp) x[rp] = cmul(x[rp], tw2[rp-1]);
  #pragma unroll
  for (int rp = 0; rp < 8; ++rp) {         // writer: r=hi, b''=lo
    int idx = 64*hi + 8*(rp ^ hi) + (lo ^ rp);
    re[idx] = x[rp].x; im[idx] = x[rp].y;
  }
  __builtin_amdgcn_wave_barrier();
  #pragma unroll
  for (int bp = 0; bp < 8; ++bp) {         // reader: r=hi, r'=lo
    int idx = 64*hi + 8*(lo ^ hi) + (bp ^ lo);
    x[bp] = make_float2(re[idx], im[idx]);
  }
  __builtin_amdgcn_wave_barrier();
  fft8(x);                                  // x[q] = X[hi + 8*lo + 64q]
}

#define TWIDDLE_INIT(tw1, tw2, lane)                                        \
  {                                                                         \
    float sv, cv;                                                           \
    __sincosf(-6.283185307179586f * (float)(lane) / 512.f, &sv, &cv);       \
    float2 w1 = make_float2(cv, sv);                                        \
    tw1[0] = w1;                                                            \
    _Pragma("unroll")                                                       \
    for (int r = 1; r < 7; ++r) tw1[r] = cmul(tw1[r-1], w1);                \
    __sincosf(-6.283185307179586f * (float)((lane) & 7) / 64.f, &sv, &cv);  \
    float2 w2 = make_float2(cv, sv);                                        \
    tw2[0] = w2;                                                            \
    _Pragma("unroll")                                                       \
    for (int r = 1; r < 7; ++r) tw2[r] = cmul(tw2[r-1], w2);                \
  }

// ---------------------------------------------------------------------------
// Row pass: 2-for-1 packed real row FFTs. Block = 4 waves; wave does 4 row
// pairs. Output transposed, cols 0..256: outT[img][col][row], float2.
// ---------------------------------------------------------------------------
__global__ __launch_bounds__(256, 4) void fft_rows_T(
    const float* __restrict__ xin, const float* __restrict__ rin,
    float2* __restrict__ outT, int img0)
{
  __shared__ float s_re[4][512], s_im[4][512];
  const int tid = threadIdx.x, w = tid >> 6, lane = tid & 63;
  const int imgL = blockIdx.x >> 4, blkin = blockIdx.x & 15;
  const int img = img0 + imgL;
  const float* base = (img < 48) ? (xin + (size_t)img * 262144)
                                 : (rin + (size_t)(img - 48) * 262144);
  float2 tw1[7], tw2[7];
  TWIDDLE_INIT(tw1, tw2, lane)
  float* re = s_re[w]; float* im = s_im[w];
  float2* outImg = outT + (size_t)imgL * ((size_t)NCOL * 512);

  for (int i = 0; i < 4; ++i) {
    const int rp = blkin * 16 + i * 4 + w;            // row pair: rows 2rp,2rp+1
    const float* rsrc = base + (size_t)rp * 1024;
    float2 x[8];
    #pragma unroll
    for (int a = 0; a < 8; ++a)
      x[a] = make_float2(rsrc[64*a + lane], rsrc[512 + 64*a + lane]);
    wave_fft512(x, re, im, tw1, tw2, lane);
    // store Z natural order (bank-free: digit-swapped index is bijective)
    #pragma unroll
    for (int q = 0; q < 8; ++q) {
      int k = (lane >> 3) + 8 * (lane & 7) + 64 * q;
      re[k] = x[q].x; im[k] = x[q].y;
    }
    __builtin_amdgcn_wave_barrier();
    // conjugate-symmetry separation: A=row 2rp spectrum, B=row 2rp+1 spectrum
    #pragma unroll
    for (int a = 0; a < 4; ++a) {
      int k  = 64 * a + lane;
      int pk = (512 - k) & 511;
      float zr = re[k],  zi = im[k];
      float pr = re[pk], pi = im[pk];
      float4 o;
      o.x = 0.5f * (zr + pr);  o.y = 0.5f * (zi - pi);   // A[k]
      o.z = 0.5f * (zi + pi);  o.w = 0.5f * (pr - zr);   // B[k]
      *reinterpret_cast<float4*>(outImg + ((size_t)k * 512 + 2 * rp)) = o;
    }
    if (lane == 0) {   // col 256 (self-paired)
      float4 o = make_float4(re[256], 0.f, im[256], 0.f);
      *reinterpret_cast<float4*>(outImg + ((size_t)256 * 512 + 2 * rp)) = o;
    }
    __builtin_amdgcn_wave_barrier();
  }
}

// ---------------------------------------------------------------------------
// Col pass: wave-local FFT per column + fused power/radial-bin (Hermitian
// weight). Block = 4 waves, 17 blocks/img (68 wave-slots, cols c=v+68k<=256).
// ---------------------------------------------------------------------------
__global__ __launch_bounds__(256, 4) void fft_cols_bin(
    const float2* __restrict__ inT, float* __restrict__ profSum, int img0)
{
  __shared__ float s_re[4][512], s_im[4][512];
  __shared__ float s_bins[4][64];
  const int tid = threadIdx.x, w = tid >> 6, lane = tid & 63;
  const int imgL = blockIdx.x / 17, blkin = blockIdx.x - imgL * 17;
  const int imgG = img0 + imgL;
  const int v = blkin * 4 + w;
  s_bins[w][lane] = 0.f;
  float2 tw1[7], tw2[7];
  TWIDDLE_INIT(tw1, tw2, lane)
  const int low6 = (lane >> 3) + 8 * (lane & 7);

  for (int c = v; c <= 256; c += 68) {
    const float2* src = inT + ((size_t)(imgL * NCOL + c)) * 512;
    float2 x[8];
    #pragma unroll
    for (int a = 0; a < 8; ++a) x[a] = src[64 * a + lane];
    wave_fft512(x, s_re[w], s_im[w], tw1, tw2, lane);
    const float wf  = (c == 0 || c == 256) ? 1.f : 2.f;
    const float sx2 = (float)(c * c);           // (-256)^2 == 256^2
    #pragma unroll
    for (int q = 0; q < 8; ++q) {
      int kout = low6 + 64 * q;
      int sy = (q >= 4) ? (kout - 512) : kout;
      float p = wf * (x[q].x * x[q].x + x[q].y * x[q].y);
      float r = sqrtf((float)(sy * sy) + sx2);
      int bb = (int)(r * 0.1953125f);           // 50/256 exact in binary
      if (bb < NB) atomicAdd(&s_bins[w][bb], p);
    }
  }
  __builtin_amdgcn_wave_barrier();
  if (lane < NB) atomicAdd(&profSum[(size_t)imgG * NB + lane], s_bins[w][lane]);
}

// ---------------------------------------------------------------------------
// Radial bin counts (geometry only). 128 blocks x 2048 pixels.
// ---------------------------------------------------------------------------
__global__ __launch_bounds__(256) void compute_counts(float* __restrict__ cnt)
{
  const int t = threadIdx.x;
  __shared__ float lb[NB];
  if (t < NB) lb[t] = 0.f;
  __syncthreads();
  const int base = blockIdx.x * 2048;
  #pragma unroll
  for (int k = 0; k < 8; ++k) {
    const int idx = base + k * 256 + t;
    const int y  = idx >> 9;
    const int xx = idx & 511;
    const int sy = (y < 256) ? y : y - 512;
    const int sx = (xx < 256) ? xx : xx - 512;
    float r = sqrtf((float)(sy * sy + sx * sx));
    int bb = (int)(r * 0.1953125f);
    if (bb < NB) atomicAdd(&lb[bb], 1.f);
  }
  __syncthreads();
  if (t < NB) atomicAdd(&cnt[t], lb[t]);
}

// ---------------------------------------------------------------------------
// Finalize: profile means -> log_softmax -> KL. One block per batch.
// ---------------------------------------------------------------------------
__global__ __launch_bounds__(256) void finalize_kl(
    const float* __restrict__ profSum, const float* __restrict__ cntg,
    float* __restrict__ out)
{
  const int b = blockIdx.x;
  const int t = threadIdx.x;
  __shared__ float red[256];

  float lxv = -3.0e38f, lrv = -3.0e38f;
  if (t < 150) {
    const int cc  = t / NB;
    const int bin = t - cc * NB;
    const float c = cntg[bin];
    lxv = profSum[(size_t)(b * 3 + cc) * NB + bin] / c;
    lrv = profSum[(size_t)(48 + b * 3 + cc) * NB + bin] / c;
  }
  auto rmax = [&](float v) {
    red[t] = v; __syncthreads();
    for (int s2 = 128; s2 >= 1; s2 >>= 1) {
      if (t < s2) red[t] = fmaxf(red[t], red[t + s2]);
      __syncthreads();
    }
    float rr = red[0]; __syncthreads();
    return rr;
  };
  auto rsum = [&](float v) {
    red[t] = v; __syncthreads();
    for (int s2 = 128; s2 >= 1; s2 >>= 1) {
      if (t < s2) red[t] = red[t] + red[t + s2];
      __syncthreads();
    }
    float rr = red[0]; __syncthreads();
    return rr;
  };
  const float mx  = rmax(lxv);
  const float mr  = rmax(lrv);
  const float sx  = rsum((t < 150) ? expf(lxv - mx) : 0.f);
  const float sr  = rsum((t < 150) ? expf(lrv - mr) : 0.f);
  const float lsx = logf(sx);
  const float lsr = logf(sr);
  float term = 0.f;
  if (t < 150) {
    const float logp = lxv - mx - lsx;
    const float logq = lrv - mr - lsr;
    const float q    = expf(logq);
    term = q * (logq - logp);
  }
  const float div = rsum(term);
  if (t == 0) out[b] = div;
}

// ---------------------------------------------------------------------------
extern "C" void kernel_launch(void* const* d_in, const int* in_sizes, int n_in,
                              void* d_out, int out_size, void* d_ws, size_t ws_size,
                              hipStream_t stream)
{
  const float* x = (const float*)d_in[0];
  const float* r = (const float*)d_in[1];
  float* out     = (float*)d_out;

  // ws layout: [0,19200) profile sums (96x50); [19200,19400) bin counts;
  // [19456, ...) chunked transposed-spectrum intermediate (257 cols/img).
  float* profSum = (float*)d_ws;
  float* cnt     = (float*)((char*)d_ws + 19200);
  const size_t IM_OFS = 19456;
  float2* interT = (float2*)((char*)d_ws + IM_OFS);

  const size_t perImg = (size_t)NCOL * 512 * sizeof(float2);  // ~1.03 MiB
  size_t avail = (ws_size > IM_OFS) ? (ws_size - IM_OFS) : 0;
  int ic = (int)(avail / perImg);
  if (ic > NIMG) ic = NIMG;
  if (ic < 1) ic = 1;

  hipMemsetAsync(d_ws, 0, IM_OFS, stream);
  hipLaunchKernelGGL(compute_counts, dim3(128), dim3(256), 0, stream, cnt);

  for (int img0 = 0; img0 < NIMG; img0 += ic) {
    const int n = (NIMG - img0 < ic) ? (NIMG - img0) : ic;
    hipLaunchKernelGGL(fft_rows_T, dim3(n * 16), dim3(256), 0, stream,
                       x, r, interT, img0);
    hipLaunchKernelGGL(fft_cols_bin, dim3(n * 17), dim3(256), 0, stream,
                       interT, profSum, img0);
  }
  hipLaunchKernelGGL(finalize_kl, dim3(16), dim3(256), 0, stream,
                     profSum, cnt, out);
}

// Round 4
// 129.671 us; speedup vs baseline: 5.2622x; 1.1827x over previous
//
#include <hip/hip_runtime.h>

// SpectralDivergence: fft2(512x512) power spectrum -> radial profile (50 bins)
// -> per-batch KL divergence between softmaxed profiles of x and reference.
// 96 images (48 x + 48 ref), B=16, C=3, H=W=512. Output: 16 floats.
//
// R3: occupancy attack. One 512-pt FFT per WAVE (no per-wave serial loop):
// rows grid = ic*64 blocks, cols grid = ic*65 blocks (~12 blocks/CU vs 3).
// LDS exchanges use interleaved float2 + ds_*_b64 (half the LDS ops of the
// split re/im b32 version); XOR swizzles re-verified conflict-free at
// 16-lane (b64) granularity. Cols bins aggregated per block (1 syncthreads).

#define NIMG 96
#define NB 50
#define NCOL 257

__device__ __forceinline__ float2 cadd(float2 a, float2 b){ return make_float2(a.x+b.x, a.y+b.y); }
__device__ __forceinline__ float2 csub(float2 a, float2 b){ return make_float2(a.x-b.x, a.y-b.y); }
__device__ __forceinline__ float2 cmul(float2 a, float2 b){
  return make_float2(fmaf(a.x, b.x, -(a.y*b.y)), fmaf(a.x, b.y, a.y*b.x));
}
__device__ __forceinline__ float2 mul_mi(float2 a){ return make_float2(a.y, -a.x); }  // * -i

// 8-point DFT, natural order: g[r] <- sum_a g[a] * W8^{a r}
__device__ __forceinline__ void fft8(float2 g[8]) {
  const float C = 0.70710678118654752f;
  float2 e0=g[0], e1=g[2], e2=g[4], e3=g[6];
  float2 o0=g[1], o1=g[3], o2=g[5], o3=g[7];
  float2 t0=cadd(e0,e2), t1=csub(e0,e2), t2=cadd(e1,e3), t3m=mul_mi(csub(e1,e3));
  float2 E0=cadd(t0,t2), E1=cadd(t1,t3m), E2=csub(t0,t2), E3=csub(t1,t3m);
  float2 s0=cadd(o0,o2), s1=csub(o0,o2), s2=cadd(o1,o3), s3m=mul_mi(csub(o1,o3));
  float2 O0=cadd(s0,s2), O1=cadd(s1,s3m), O2=csub(s0,s2), O3=csub(s1,s3m);
  O1 = make_float2(C*(O1.x+O1.y), C*(O1.y-O1.x));      // * W8^1
  O2 = mul_mi(O2);                                      // * W8^2
  O3 = make_float2(C*(O3.y-O3.x), -C*(O3.x+O3.y));      // * W8^3
  g[0]=cadd(E0,O0); g[4]=csub(E0,O0);
  g[1]=cadd(E1,O1); g[5]=csub(E1,O1);
  g[2]=cadd(E2,O2); g[6]=csub(E2,O2);
  g[3]=cadd(E3,O3); g[7]=csub(E3,O3);
}

// Wave-local 512-pt FFT. Input: x[a] = data[64a + lane]. Output:
// x[q] = X[(lane>>3) + 8*(lane&7) + 64*q]. z: per-wave float2[512] LDS.
// XOR-swizzled exchange layouts, conflict-free for ds_*_b64 (16-lane phases).
__device__ __forceinline__ void wave_fft512(
    float2 x[8], float2* __restrict__ z,
    const float2 tw1[7], const float2 tw2[7], int lane)
{
  const int hi = lane >> 3, lo = lane & 7;
  fft8(x);
  #pragma unroll
  for (int r = 1; r < 8; ++r) x[r] = cmul(x[r], tw1[r-1]);
  #pragma unroll
  for (int r = 0; r < 8; ++r) z[64*r + 8*(hi ^ r) + lo] = x[r];
  __builtin_amdgcn_wave_barrier();
  #pragma unroll
  for (int ap = 0; ap < 8; ++ap) x[ap] = z[64*hi + 8*(ap ^ hi) + lo];
  __builtin_amdgcn_wave_barrier();
  fft8(x);
  #pragma unroll
  for (int rp = 1; rp < 8; ++rp) x[rp] = cmul(x[rp], tw2[rp-1]);
  #pragma unroll
  for (int rp = 0; rp < 8; ++rp) z[64*hi + 8*(rp ^ hi) + (lo ^ rp)] = x[rp];
  __builtin_amdgcn_wave_barrier();
  #pragma unroll
  for (int bp = 0; bp < 8; ++bp) x[bp] = z[64*hi + 8*(lo ^ hi) + (bp ^ lo)];
  __builtin_amdgcn_wave_barrier();
  fft8(x);                                  // x[q] = X[hi + 8*lo + 64q]
}

#define TWIDDLE_INIT(tw1, tw2, lane)                                        \
  {                                                                         \
    float sv, cv;                                                           \
    __sincosf(-6.283185307179586f * (float)(lane) / 512.f, &sv, &cv);       \
    float2 w1 = make_float2(cv, sv);                                        \
    tw1[0] = w1;                                                            \
    _Pragma("unroll")                                                       \
    for (int r = 1; r < 7; ++r) tw1[r] = cmul(tw1[r-1], w1);                \
    __sincosf(-6.283185307179586f * (float)((lane) & 7) / 64.f, &sv, &cv);  \
    float2 w2 = make_float2(cv, sv);                                        \
    tw2[0] = w2;                                                            \
    _Pragma("unroll")                                                       \
    for (int r = 1; r < 7; ++r) tw2[r] = cmul(tw2[r-1], w2);                \
  }

// ---------------------------------------------------------------------------
// Row pass: 2-for-1 packed real row FFTs, ONE row pair per wave.
// Block = 4 waves = 4 row pairs; 64 blocks/image.
// Output transposed, cols 0..256: outT[img][col][row], float2.
// ---------------------------------------------------------------------------
__global__ __launch_bounds__(256, 4) void fft_rows_T(
    const float* __restrict__ xin, const float* __restrict__ rin,
    float2* __restrict__ outT, int img0)
{
  __shared__ float2 s_z[4][512];
  const int tid = threadIdx.x, w = tid >> 6, lane = tid & 63;
  const int imgL = blockIdx.x >> 6, blkin = blockIdx.x & 63;
  const int img = img0 + imgL;
  const float* base = (img < 48) ? (xin + (size_t)img * 262144)
                                 : (rin + (size_t)(img - 48) * 262144);
  const int rp = blkin * 4 + w;                     // rows 2rp, 2rp+1
  const float* rsrc = base + (size_t)rp * 1024;

  float2 tw1[7], tw2[7];
  TWIDDLE_INIT(tw1, tw2, lane)
  float2* z = s_z[w];
  float2* outImg = outT + (size_t)imgL * ((size_t)NCOL * 512);

  float2 x[8];
  #pragma unroll
  for (int a = 0; a < 8; ++a)
    x[a] = make_float2(rsrc[64*a + lane], rsrc[512 + 64*a + lane]);
  wave_fft512(x, z, tw1, tw2, lane);

  // natural-order store (b64; 4-way on 8 ops — cheaper than 16 b32 @ 2-way)
  #pragma unroll
  for (int q = 0; q < 8; ++q)
    z[(lane >> 3) + 8 * (lane & 7) + 64 * q] = x[q];
  __builtin_amdgcn_wave_barrier();

  // conjugate-symmetry separation: A=row 2rp spectrum, B=row 2rp+1 spectrum
  #pragma unroll
  for (int a = 0; a < 4; ++a) {
    int k  = 64 * a + lane;
    int pk = (512 - k) & 511;
    float2 zk = z[k], zp = z[pk];
    float4 o;
    o.x = 0.5f * (zk.x + zp.x);  o.y = 0.5f * (zk.y - zp.y);   // A[k]
    o.z = 0.5f * (zk.y + zp.y);  o.w = 0.5f * (zp.x - zk.x);   // B[k]
    *reinterpret_cast<float4*>(outImg + ((size_t)k * 512 + 2 * rp)) = o;
  }
  if (lane == 0) {   // col 256 (self-paired)
    float2 zn = z[256];
    float4 o = make_float4(zn.x, 0.f, zn.y, 0.f);
    *reinterpret_cast<float4*>(outImg + ((size_t)256 * 512 + 2 * rp)) = o;
  }
}

// ---------------------------------------------------------------------------
// Col pass: ONE column FFT per wave + fused power/radial-bin (Hermitian
// weight). Block = 4 waves = 4 columns; 65 blocks/image (cols 0..256).
// ---------------------------------------------------------------------------
__global__ __launch_bounds__(256, 4) void fft_cols_bin(
    const float2* __restrict__ inT, float* __restrict__ profSum, int img0)
{
  __shared__ float2 s_z[4][512];
  __shared__ float s_bins[4][64];
  const int tid = threadIdx.x, w = tid >> 6, lane = tid & 63;
  const int imgL = blockIdx.x / 65, blkin = blockIdx.x - imgL * 65;
  const int imgG = img0 + imgL;
  const int c = blkin * 4 + w;
  s_bins[w][lane] = 0.f;   // wave-private: no block sync needed before use

  if (c <= 256) {
    float2 tw1[7], tw2[7];
    TWIDDLE_INIT(tw1, tw2, lane)
    const float2* src = inT + ((size_t)(imgL * NCOL + c)) * 512;
    float2 x[8];
    #pragma unroll
    for (int a = 0; a < 8; ++a) x[a] = src[64 * a + lane];
    wave_fft512(x, s_z[w], tw1, tw2, lane);

    const float wf  = (c == 0 || c == 256) ? 1.f : 2.f;
    const float sx2 = (float)(c * c);           // (-256)^2 == 256^2
    const int low6 = (lane >> 3) + 8 * (lane & 7);
    #pragma unroll
    for (int q = 0; q < 8; ++q) {
      int kout = low6 + 64 * q;
      int sy = (q >= 4) ? (kout - 512) : kout;
      float p = wf * (x[q].x * x[q].x + x[q].y * x[q].y);
      float r = sqrtf((float)(sy * sy) + sx2);
      int bb = (int)(r * 0.1953125f);           // 50/256 exact in binary
      if (bb < NB) atomicAdd(&s_bins[w][bb], p);
    }
  }
  __syncthreads();
  if (tid < NB) {
    float s = s_bins[0][tid] + s_bins[1][tid] + s_bins[2][tid] + s_bins[3][tid];
    atomicAdd(&profSum[(size_t)imgG * NB + tid], s);
  }
}

// ---------------------------------------------------------------------------
// Radial bin counts (geometry only). 128 blocks x 2048 pixels.
// ---------------------------------------------------------------------------
__global__ __launch_bounds__(256) void compute_counts(float* __restrict__ cnt)
{
  const int t = threadIdx.x;
  __shared__ float lb[NB];
  if (t < NB) lb[t] = 0.f;
  __syncthreads();
  const int base = blockIdx.x * 2048;
  #pragma unroll
  for (int k = 0; k < 8; ++k) {
    const int idx = base + k * 256 + t;
    const int y  = idx >> 9;
    const int xx = idx & 511;
    const int sy = (y < 256) ? y : y - 512;
    const int sx = (xx < 256) ? xx : xx - 512;
    float r = sqrtf((float)(sy * sy + sx * sx));
    int bb = (int)(r * 0.1953125f);
    if (bb < NB) atomicAdd(&lb[bb], 1.f);
  }
  __syncthreads();
  if (t < NB) atomicAdd(&cnt[t], lb[t]);
}

// ---------------------------------------------------------------------------
// Finalize: profile means -> log_softmax -> KL. One block per batch.
// ---------------------------------------------------------------------------
__global__ __launch_bounds__(256) void finalize_kl(
    const float* __restrict__ profSum, const float* __restrict__ cntg,
    float* __restrict__ out)
{
  const int b = blockIdx.x;
  const int t = threadIdx.x;
  __shared__ float red[256];

  float lxv = -3.0e38f, lrv = -3.0e38f;
  if (t < 150) {
    const int cc  = t / NB;
    const int bin = t - cc * NB;
    const float c = cntg[bin];
    lxv = profSum[(size_t)(b * 3 + cc) * NB + bin] / c;
    lrv = profSum[(size_t)(48 + b * 3 + cc) * NB + bin] / c;
  }
  auto rmax = [&](float v) {
    red[t] = v; __syncthreads();
    for (int s2 = 128; s2 >= 1; s2 >>= 1) {
      if (t < s2) red[t] = fmaxf(red[t], red[t + s2]);
      __syncthreads();
    }
    float rr = red[0]; __syncthreads();
    return rr;
  };
  auto rsum = [&](float v) {
    red[t] = v; __syncthreads();
    for (int s2 = 128; s2 >= 1; s2 >>= 1) {
      if (t < s2) red[t] = red[t] + red[t + s2];
      __syncthreads();
    }
    float rr = red[0]; __syncthreads();
    return rr;
  };
  const float mx  = rmax(lxv);
  const float mr  = rmax(lrv);
  const float sx  = rsum((t < 150) ? expf(lxv - mx) : 0.f);
  const float sr  = rsum((t < 150) ? expf(lrv - mr) : 0.f);
  const float lsx = logf(sx);
  const float lsr = logf(sr);
  float term = 0.f;
  if (t < 150) {
    const float logp = lxv - mx - lsx;
    const float logq = lrv - mr - lsr;
    const float q    = expf(logq);
    term = q * (logq - logp);
  }
  const float div = rsum(term);
  if (t == 0) out[b] = div;
}

// ---------------------------------------------------------------------------
extern "C" void kernel_launch(void* const* d_in, const int* in_sizes, int n_in,
                              void* d_out, int out_size, void* d_ws, size_t ws_size,
                              hipStream_t stream)
{
  const float* x = (const float*)d_in[0];
  const float* r = (const float*)d_in[1];
  float* out     = (float*)d_out;

  // ws layout: [0,19200) profile sums (96x50); [19200,19400) bin counts;
  // [19456, ...) chunked transposed-spectrum intermediate (257 cols/img).
  float* profSum = (float*)d_ws;
  float* cnt     = (float*)((char*)d_ws + 19200);
  const size_t IM_OFS = 19456;
  float2* interT = (float2*)((char*)d_ws + IM_OFS);

  const size_t perImg = (size_t)NCOL * 512 * sizeof(float2);  // ~1.03 MiB
  size_t avail = (ws_size > IM_OFS) ? (ws_size - IM_OFS) : 0;
  int ic = (int)(avail / perImg);
  if (ic > NIMG) ic = NIMG;
  if (ic < 1) ic = 1;

  hipMemsetAsync(d_ws, 0, IM_OFS, stream);
  hipLaunchKernelGGL(compute_counts, dim3(128), dim3(256), 0, stream, cnt);

  for (int img0 = 0; img0 < NIMG; img0 += ic) {
    const int n = (NIMG - img0 < ic) ? (NIMG - img0) : ic;
    hipLaunchKernelGGL(fft_rows_T, dim3(n * 64), dim3(256), 0, stream,
                       x, r, interT, img0);
    hipLaunchKernelGGL(fft_cols_bin, dim3(n * 65), dim3(256), 0, stream,
                       interT, profSum, img0);
  }
  hipLaunchKernelGGL(finalize_kl, dim3(16), dim3(256), 0, stream,
                     profSum, cnt, out);
}

// Round 5
// 109.515 us; speedup vs baseline: 6.2307x; 1.1840x over previous
//
#include <hip/hip_runtime.h>

// SpectralDivergence: fft2(512x512) power spectrum -> radial profile (50 bins)
// -> per-batch KL divergence between softmaxed profiles of x and reference.
// 96 images (48 x + 48 ref), B=16, C=3, H=W=512. Output: 16 floats.
//
// R4: (1) PHYS xor-swizzle kills the 4-way bank conflict of the natural-order
// store (2.36M conflict cycles); (2) rows output staged in LDS and written as
// 64B-contiguous chunks (was 16B @ 4KB stride, 25% sector fill); (3) bf16-
// packed intermediate (uint per complex): halves traffic and fits all 96
// images in one workspace chunk -> single rows+cols pass, fewer launches.

#define NIMG 96
#define NB 50
#define NCOL 257
#define PHYS(k) ((k) ^ (((k) >> 3) & 7))

typedef unsigned int uint32;

__device__ __forceinline__ float2 cadd(float2 a, float2 b){ return make_float2(a.x+b.x, a.y+b.y); }
__device__ __forceinline__ float2 csub(float2 a, float2 b){ return make_float2(a.x-b.x, a.y-b.y); }
__device__ __forceinline__ float2 cmul(float2 a, float2 b){
  return make_float2(fmaf(a.x, b.x, -(a.y*b.y)), fmaf(a.x, b.y, a.y*b.x));
}
__device__ __forceinline__ float2 mul_mi(float2 a){ return make_float2(a.y, -a.x); }  // * -i

// pack complex -> bf16x2 (re in high half, im in low half), RNE rounding
__device__ __forceinline__ uint32 bfpack(float re, float im) {
  uint32 ur = __float_as_uint(re); ur += 0x7FFFu + ((ur >> 16) & 1u);
  uint32 ui = __float_as_uint(im); ui += 0x7FFFu + ((ui >> 16) & 1u);
  return (ur & 0xFFFF0000u) | (ui >> 16);
}
__device__ __forceinline__ float2 bfunpack(uint32 u) {
  return make_float2(__uint_as_float(u & 0xFFFF0000u), __uint_as_float(u << 16));
}

// 8-point DFT, natural order: g[r] <- sum_a g[a] * W8^{a r}
__device__ __forceinline__ void fft8(float2 g[8]) {
  const float C = 0.70710678118654752f;
  float2 e0=g[0], e1=g[2], e2=g[4], e3=g[6];
  float2 o0=g[1], o1=g[3], o2=g[5], o3=g[7];
  float2 t0=cadd(e0,e2), t1=csub(e0,e2), t2=cadd(e1,e3), t3m=mul_mi(csub(e1,e3));
  float2 E0=cadd(t0,t2), E1=cadd(t1,t3m), E2=csub(t0,t2), E3=csub(t1,t3m);
  float2 s0=cadd(o0,o2), s1=csub(o0,o2), s2=cadd(o1,o3), s3m=mul_mi(csub(o1,o3));
  float2 O0=cadd(s0,s2), O1=cadd(s1,s3m), O2=csub(s0,s2), O3=csub(s1,s3m);
  O1 = make_float2(C*(O1.x+O1.y), C*(O1.y-O1.x));      // * W8^1
  O2 = mul_mi(O2);                                      // * W8^2
  O3 = make_float2(C*(O3.y-O3.x), -C*(O3.x+O3.y));      // * W8^3
  g[0]=cadd(E0,O0); g[4]=csub(E0,O0);
  g[1]=cadd(E1,O1); g[5]=csub(E1,O1);
  g[2]=cadd(E2,O2); g[6]=csub(E2,O2);
  g[3]=cadd(E3,O3); g[7]=csub(E3,O3);
}

// Wave-local 512-pt FFT. Input: x[a] = data[64a + lane]. Output:
// x[q] = X[(lane>>3) + 8*(lane&7) + 64*q]. z: per-wave float2[512] LDS.
// XOR-swizzled exchange layouts, conflict-free at b64 granularity.
__device__ __forceinline__ void wave_fft512(
    float2 x[8], float2* __restrict__ z,
    const float2 tw1[7], const float2 tw2[7], int lane)
{
  const int hi = lane >> 3, lo = lane & 7;
  fft8(x);
  #pragma unroll
  for (int r = 1; r < 8; ++r) x[r] = cmul(x[r], tw1[r-1]);
  #pragma unroll
  for (int r = 0; r < 8; ++r) z[64*r + 8*(hi ^ r) + lo] = x[r];
  __builtin_amdgcn_wave_barrier();
  #pragma unroll
  for (int ap = 0; ap < 8; ++ap) x[ap] = z[64*hi + 8*(ap ^ hi) + lo];
  __builtin_amdgcn_wave_barrier();
  fft8(x);
  #pragma unroll
  for (int rp = 1; rp < 8; ++rp) x[rp] = cmul(x[rp], tw2[rp-1]);
  #pragma unroll
  for (int rp = 0; rp < 8; ++rp) z[64*hi + 8*(rp ^ hi) + (lo ^ rp)] = x[rp];
  __builtin_amdgcn_wave_barrier();
  #pragma unroll
  for (int bp = 0; bp < 8; ++bp) x[bp] = z[64*hi + 8*(lo ^ hi) + (bp ^ lo)];
  __builtin_amdgcn_wave_barrier();
  fft8(x);                                  // x[q] = X[hi + 8*lo + 64q]
}

#define TWIDDLE_INIT(tw1, tw2, lane)                                        \
  {                                                                         \
    float sv, cv;                                                           \
    __sincosf(-6.283185307179586f * (float)(lane) / 512.f, &sv, &cv);       \
    float2 w1 = make_float2(cv, sv);                                        \
    tw1[0] = w1;                                                            \
    _Pragma("unroll")                                                       \
    for (int r = 1; r < 7; ++r) tw1[r] = cmul(tw1[r-1], w1);                \
    __sincosf(-6.283185307179586f * (float)((lane) & 7) / 64.f, &sv, &cv);  \
    float2 w2 = make_float2(cv, sv);                                        \
    tw2[0] = w2;                                                            \
    _Pragma("unroll")                                                       \
    for (int r = 1; r < 7; ++r) tw2[r] = cmul(tw2[r-1], w2);                \
  }

// ---------------------------------------------------------------------------
// Row pass: 2-for-1 packed real row FFTs, one row pair per wave, 8 waves per
// block (16 consecutive output rows). Output transposed bf16-packed:
// outT[img][col][row] (uint per complex), written as 64B chunks via staging.
// ---------------------------------------------------------------------------
__global__ __launch_bounds__(512, 4) void fft_rows_T(
    const float* __restrict__ xin, const float* __restrict__ rin,
    uint32* __restrict__ outT, int img0)
{
  __shared__ float2 s_z[8][512];        // 32 KB
  __shared__ uint2  s_stage[64][8];     // 4 KB
  const int tid = threadIdx.x, w = tid >> 6, lane = tid & 63;
  const int imgL = blockIdx.x >> 5, blkin = blockIdx.x & 31;
  const int img = img0 + imgL;
  const float* base = (img < 48) ? (xin + (size_t)img * 262144)
                                 : (rin + (size_t)(img - 48) * 262144);
  const int rp = blkin * 8 + w;                     // rows 2rp, 2rp+1
  const float* rsrc = base + (size_t)rp * 1024;

  float2 tw1[7], tw2[7];
  TWIDDLE_INIT(tw1, tw2, lane)
  float2* z = s_z[w];
  uint32* outImg = outT + (size_t)imgL * ((size_t)NCOL * 512);

  float2 x[8];
  #pragma unroll
  for (int a = 0; a < 8; ++a)
    x[a] = make_float2(rsrc[64*a + lane], rsrc[512 + 64*a + lane]);
  wave_fft512(x, z, tw1, tw2, lane);

  // natural-order store, PHYS-swizzled (conflict-free per quarter-wave)
  const int hi = lane >> 3, lo = lane & 7;
  #pragma unroll
  for (int q = 0; q < 8; ++q)
    z[PHYS(hi + 8*lo + 64*q)] = x[q];
  __builtin_amdgcn_wave_barrier();

  // conjugate-symmetry separation + staged 64B-coalesced transposed write
  #pragma unroll
  for (int a = 0; a < 4; ++a) {
    const int k  = 64 * a + lane;                 // 0..255
    const int pk = (512 - k) & 511;
    float2 zk = z[PHYS(k)], zp = z[PHYS(pk)];
    float Ar = 0.5f * (zk.x + zp.x), Ai = 0.5f * (zk.y - zp.y);   // row 2rp
    float Br = 0.5f * (zk.y + zp.y), Bi = 0.5f * (zp.x - zk.x);   // row 2rp+1
    s_stage[lane][(w + lane) & 7] = make_uint2(bfpack(Ar, Ai), bfpack(Br, Bi));
    __syncthreads();
    const int kk = tid >> 3, ww = tid & 7;
    uint2 v = s_stage[kk][(ww + kk) & 7];
    *reinterpret_cast<uint2*>(outImg + ((size_t)(64*a + kk) * 512
                                        + 16*blkin + 2*ww)) = v;
    __syncthreads();
  }
  if (lane == 0) {   // col 256 (self-paired): A=Re(Z), B=Im(Z)
    float2 zn = z[256];   // PHYS(256)==256
    *reinterpret_cast<uint2*>(outImg + ((size_t)256 * 512 + 2 * rp)) =
        make_uint2(bfpack(zn.x, 0.f), bfpack(zn.y, 0.f));
  }
}

// ---------------------------------------------------------------------------
// Col pass: one column FFT per wave + fused power/radial-bin (Hermitian
// weight). Block = 4 waves = 4 columns; 65 blocks/image (cols 0..256).
// ---------------------------------------------------------------------------
__global__ __launch_bounds__(256, 4) void fft_cols_bin(
    const uint32* __restrict__ inT, float* __restrict__ profSum, int img0)
{
  __shared__ float2 s_z[4][512];
  __shared__ float s_bins[4][64];
  const int tid = threadIdx.x, w = tid >> 6, lane = tid & 63;
  const int imgL = blockIdx.x / 65, blkin = blockIdx.x - imgL * 65;
  const int imgG = img0 + imgL;
  const int c = blkin * 4 + w;
  s_bins[w][lane] = 0.f;   // wave-private: no block sync needed before use

  if (c <= 256) {
    float2 tw1[7], tw2[7];
    TWIDDLE_INIT(tw1, tw2, lane)
    const uint32* src = inT + ((size_t)(imgL * NCOL + c)) * 512;
    float2 x[8];
    #pragma unroll
    for (int a = 0; a < 8; ++a) x[a] = bfunpack(src[64 * a + lane]);
    wave_fft512(x, s_z[w], tw1, tw2, lane);

    const float wf  = (c == 0 || c == 256) ? 1.f : 2.f;
    const float sx2 = (float)(c * c);           // (-256)^2 == 256^2
    const int low6 = (lane >> 3) + 8 * (lane & 7);
    #pragma unroll
    for (int q = 0; q < 8; ++q) {
      int kout = low6 + 64 * q;
      int sy = (q >= 4) ? (kout - 512) : kout;
      float p = wf * (x[q].x * x[q].x + x[q].y * x[q].y);
      float r = sqrtf((float)(sy * sy) + sx2);
      int bb = (int)(r * 0.1953125f);           // 50/256 exact in binary
      if (bb < NB) atomicAdd(&s_bins[w][bb], p);
    }
  }
  __syncthreads();
  if (tid < NB) {
    float s = s_bins[0][tid] + s_bins[1][tid] + s_bins[2][tid] + s_bins[3][tid];
    atomicAdd(&profSum[(size_t)imgG * NB + tid], s);
  }
}

// ---------------------------------------------------------------------------
// Radial bin counts (geometry only). 128 blocks x 2048 pixels.
// ---------------------------------------------------------------------------
__global__ __launch_bounds__(256) void compute_counts(float* __restrict__ cnt)
{
  const int t = threadIdx.x;
  __shared__ float lb[NB];
  if (t < NB) lb[t] = 0.f;
  __syncthreads();
  const int base = blockIdx.x * 2048;
  #pragma unroll
  for (int k = 0; k < 8; ++k) {
    const int idx = base + k * 256 + t;
    const int y  = idx >> 9;
    const int xx = idx & 511;
    const int sy = (y < 256) ? y : y - 512;
    const int sx = (xx < 256) ? xx : xx - 512;
    float r = sqrtf((float)(sy * sy + sx * sx));
    int bb = (int)(r * 0.1953125f);
    if (bb < NB) atomicAdd(&lb[bb], 1.f);
  }
  __syncthreads();
  if (t < NB) atomicAdd(&cnt[t], lb[t]);
}

// ---------------------------------------------------------------------------
// Finalize: profile means -> log_softmax -> KL. One block per batch.
// ---------------------------------------------------------------------------
__global__ __launch_bounds__(256) void finalize_kl(
    const float* __restrict__ profSum, const float* __restrict__ cntg,
    float* __restrict__ out)
{
  const int b = blockIdx.x;
  const int t = threadIdx.x;
  __shared__ float red[256];

  float lxv = -3.0e38f, lrv = -3.0e38f;
  if (t < 150) {
    const int cc  = t / NB;
    const int bin = t - cc * NB;
    const float c = cntg[bin];
    lxv = profSum[(size_t)(b * 3 + cc) * NB + bin] / c;
    lrv = profSum[(size_t)(48 + b * 3 + cc) * NB + bin] / c;
  }
  auto rmax = [&](float v) {
    red[t] = v; __syncthreads();
    for (int s2 = 128; s2 >= 1; s2 >>= 1) {
      if (t < s2) red[t] = fmaxf(red[t], red[t + s2]);
      __syncthreads();
    }
    float rr = red[0]; __syncthreads();
    return rr;
  };
  auto rsum = [&](float v) {
    red[t] = v; __syncthreads();
    for (int s2 = 128; s2 >= 1; s2 >>= 1) {
      if (t < s2) red[t] = red[t] + red[t + s2];
      __syncthreads();
    }
    float rr = red[0]; __syncthreads();
    return rr;
  };
  const float mx  = rmax(lxv);
  const float mr  = rmax(lrv);
  const float sx  = rsum((t < 150) ? expf(lxv - mx) : 0.f);
  const float sr  = rsum((t < 150) ? expf(lrv - mr) : 0.f);
  const float lsx = logf(sx);
  const float lsr = logf(sr);
  float term = 0.f;
  if (t < 150) {
    const float logp = lxv - mx - lsx;
    const float logq = lrv - mr - lsr;
    const float q    = expf(logq);
    term = q * (logq - logp);
  }
  const float div = rsum(term);
  if (t == 0) out[b] = div;
}

// ---------------------------------------------------------------------------
extern "C" void kernel_launch(void* const* d_in, const int* in_sizes, int n_in,
                              void* d_out, int out_size, void* d_ws, size_t ws_size,
                              hipStream_t stream)
{
  const float* x = (const float*)d_in[0];
  const float* r = (const float*)d_in[1];
  float* out     = (float*)d_out;

  // ws layout: [0,19200) profile sums (96x50); [19200,19400) bin counts;
  // [19456, ...) chunked bf16-packed transposed spectrum (257 cols/img).
  float* profSum = (float*)d_ws;
  float* cnt     = (float*)((char*)d_ws + 19200);
  const size_t IM_OFS = 19456;
  uint32* interT = (uint32*)((char*)d_ws + IM_OFS);

  const size_t perImg = (size_t)NCOL * 512 * sizeof(uint32);  // ~514 KiB
  size_t avail = (ws_size > IM_OFS) ? (ws_size - IM_OFS) : 0;
  int ic = (int)(avail / perImg);
  if (ic > NIMG) ic = NIMG;
  if (ic < 1) ic = 1;

  hipMemsetAsync(d_ws, 0, IM_OFS, stream);
  hipLaunchKernelGGL(compute_counts, dim3(128), dim3(256), 0, stream, cnt);

  for (int img0 = 0; img0 < NIMG; img0 += ic) {
    const int n = (NIMG - img0 < ic) ? (NIMG - img0) : ic;
    hipLaunchKernelGGL(fft_rows_T, dim3(n * 32), dim3(512), 0, stream,
                       x, r, interT, img0);
    hipLaunchKernelGGL(fft_cols_bin, dim3(n * 65), dim3(256), 0, stream,
                       interT, profSum, img0);
  }
  hipLaunchKernelGGL(finalize_kl, dim3(16), dim3(256), 0, stream,
                     profSum, cnt, out);
}